// Round 1
// 131.699 us; speedup vs baseline: 1.0254x; 1.0254x over previous
//
#include <hip/hip_runtime.h>
#include <math.h>

// Problem shapes
// feature: (16, 32, 64, 64) f32
// img:     (16, 3, 512, 512) f32
// conv_w:  (16, 32, 16, 16) f32   (OIHW)
// conv_b:  (16,)
// lin_w:   (25, 144)
// lin_b:   (25,)
// out:     (16, 3, 512, 512) f32

#define B_  16
#define C_  3
#define H_  512
#define W_  512

// ---------------------------------------------------------------------------
// Stage 1: 16x16 conv (pad=1) on the 16x16 feature patch + bias + exact gelu.
// One block per (b, oc); thread <-> spatial tap for all 32 input channels.
// Writes g[b, oc*9 + k] (post-gelu), consumed by the fused depthwise kernel.
// ---------------------------------------------------------------------------
__global__ __launch_bounds__(256) void patch_conv_kernel(
    const float* __restrict__ feature,
    const float* __restrict__ conv_w,
    const float* __restrict__ conv_b,
    float* __restrict__ g_out)
{
    __shared__ float patch_raw[17 + 8192 + 17]; // guard pads for +-17 offsets
    __shared__ float red[9][4];
    float* patch = patch_raw + 17;

    int blk = blockIdx.x;
    int b   = blk >> 4;
    int oc  = blk & 15;
    int tid = threadIdx.x;

    const float* fb = feature + (size_t)b * 32 * 4096;
    const float* wb = conv_w + (size_t)oc * 8192;

    if (tid < 17) { patch_raw[tid] = 0.f; patch_raw[17 + 8192 + tid] = 0.f; }

    for (int i = tid; i < 8192; i += 256) {
        int ic = i >> 8;
        int r  = i & 255;
        patch[i] = fb[ic * 4096 + (r >> 4) * 64 + (r & 15)];
    }

    float wreg[32];
    #pragma unroll
    for (int ic = 0; ic < 32; ic++) wreg[ic] = wb[ic * 256 + tid];

    __syncthreads();

    int kh = tid >> 4;
    int kw = tid & 15;

    float acc[9];
    #pragma unroll
    for (int k = 0; k < 9; k++) acc[k] = 0.f;

    #pragma unroll 4
    for (int ic = 0; ic < 32; ic++) {
        int base = ic * 256 + tid;
        float wv = wreg[ic];
        #pragma unroll
        for (int di = 0; di < 3; di++) {
            #pragma unroll
            for (int dj = 0; dj < 3; dj++) {
                acc[di * 3 + dj] += patch[base + (di - 1) * 16 + (dj - 1)] * wv;
            }
        }
    }

    #pragma unroll
    for (int di = 0; di < 3; di++) {
        #pragma unroll
        for (int dj = 0; dj < 3; dj++) {
            bool ok = ((unsigned)(kh + di - 1) < 16u) &&
                      ((unsigned)(kw + dj - 1) < 16u);
            if (!ok) acc[di * 3 + dj] = 0.f;
        }
    }

    #pragma unroll
    for (int k = 0; k < 9; k++) {
        float v = acc[k];
        #pragma unroll
        for (int off = 32; off > 0; off >>= 1)
            v += __shfl_xor(v, off, 64);
        acc[k] = v;
    }
    int wid  = tid >> 6;
    int lane = tid & 63;
    if (lane == 0) {
        #pragma unroll
        for (int k = 0; k < 9; k++) red[k][wid] = acc[k];
    }
    __syncthreads();
    if (tid < 9) {
        float s = red[tid][0] + red[tid][1] + red[tid][2] + red[tid][3];
        s += conv_b[oc];
        float g = 0.5f * s * (1.0f + erff(s * 0.70710678118654752f));
        g_out[(b * 16 + oc) * 9 + tid] = g;
    }
}

// ---------------------------------------------------------------------------
// Stage 2+3 fused: depthwise 5x5 conv, reflect pad=2, with the 25x144 GEMV
// (kernel_v = gelu_feats @ lin_w.T + lin_b) recomputed redundantly per block.
// The GEMV input fetch (g: 576B, lin_w: 14.4KB -> L2-hot) overlaps the
// already-issued img row prefetch loads, so its latency hides.
//
// Block tile 64 wide x 128 tall; 256 threads, each 4 wide x 8 tall.
// Each thread streams its 12 input rows through a 4-deep register window.
// ---------------------------------------------------------------------------
#define TSX  64          // tile width
#define TSY  128         // tile height

__device__ __forceinline__ int reflect_idx(int v, int n) {
    v = (v < 0) ? -v : v;
    v = (v >= n) ? (2 * n - 2 - v) : v;
    return v;
}

template <bool XFAST>
__device__ __forceinline__ void dw_tile_fused(
    const float* __restrict__ ip, float* __restrict__ op,
    const float* __restrict__ gb,      // g + b*144
    const float* __restrict__ lin_w,
    const float* __restrict__ lin_b,
    float* __restrict__ kv_lds,        // 32-float LDS scratch
    int ty0, int tx0, int tx, int tyl, int tid)
{
    int gx0 = tx0 + tx;            // x of this thread's first output column
    int xid[8];
    if (!XFAST) {
        #pragma unroll
        for (int j = 0; j < 8; j++) xid[j] = reflect_idx(gx0 - 2 + j, W_);
    }

    float win[4][8];

    // prefetch rows 0..3 (VMEM in flight; GEMV below overlaps this latency)
    #pragma unroll
    for (int r = 0; r < 4; r++) {
        int gy = reflect_idx(ty0 + tyl + r - 2, H_);
        const float* rowp = ip + (size_t)gy * W_;
        if (XFAST) {
            const float* rp = rowp + gx0;
            float2 a = *(const float2*)(rp - 2);
            float4 m = *(const float4*)(rp);
            float2 c = *(const float2*)(rp + 4);
            win[r][0] = a.x; win[r][1] = a.y;
            win[r][2] = m.x; win[r][3] = m.y; win[r][4] = m.z; win[r][5] = m.w;
            win[r][6] = c.x; win[r][7] = c.y;
        } else {
            #pragma unroll
            for (int j = 0; j < 8; j++) win[r][j] = rowp[xid[j]];
        }
    }

    // ---- redundant per-block GEMV: kv[k] = lin_b[k] + sum_j gb[j]*lin_w[k,j]
    // threads 0..199: (k = tid/8, s = tid%8), 18 strided terms each,
    // 3-level shuffle reduce within the 8-lane group.
    if (tid < 200) {
        int k = tid >> 3;          // 0..24
        int s = tid & 7;
        const float* wr = lin_w + k * 144;
        float p = 0.f;
        #pragma unroll
        for (int i = 0; i < 18; i++)
            p += gb[s + 8 * i] * wr[s + 8 * i];
        p += __shfl_xor(p, 1, 64);
        p += __shfl_xor(p, 2, 64);
        p += __shfl_xor(p, 4, 64);
        if (s == 0) kv_lds[k] = p + lin_b[k];
    }
    __syncthreads();

    // block-uniform kernel weights, forced to SGPRs
    float w[25];
    #pragma unroll
    for (int i = 0; i < 25; i++)
        w[i] = __int_as_float(
            __builtin_amdgcn_readfirstlane(__float_as_int(kv_lds[i])));

    float acc[8][4];
    #pragma unroll
    for (int i = 0; i < 8; i++)
        #pragma unroll
        for (int j = 0; j < 4; j++) acc[i][j] = 0.f;

    // stream 12 rows; consume row r, prefetch row r+4 into the freed slot
    #pragma unroll
    for (int r = 0; r < 12; r++) {
        const float* x = win[r & 3];
        #pragma unroll
        for (int orow = 0; orow < 8; orow++) {
            int dy = r - orow;
            if (dy >= 0 && dy < 5) {            // compile-time after unroll
                #pragma unroll
                for (int dx = 0; dx < 5; dx++) {
                    float wv = w[dy * 5 + dx];
                    #pragma unroll
                    for (int oc = 0; oc < 4; oc++)
                        acc[orow][oc] += wv * x[oc + dx];
                }
            }
        }
        if (r + 4 < 12) {
            int rn = r + 4;
            int gy = reflect_idx(ty0 + tyl + rn - 2, H_);
            const float* rowp = ip + (size_t)gy * W_;
            float* wdst = win[r & 3];
            if (XFAST) {
                const float* rp = rowp + gx0;
                float2 a = *(const float2*)(rp - 2);
                float4 m = *(const float4*)(rp);
                float2 c = *(const float2*)(rp + 4);
                wdst[0] = a.x; wdst[1] = a.y;
                wdst[2] = m.x; wdst[3] = m.y; wdst[4] = m.z; wdst[5] = m.w;
                wdst[6] = c.x; wdst[7] = c.y;
            } else {
                #pragma unroll
                for (int j = 0; j < 8; j++) wdst[j] = rowp[xid[j]];
            }
        }
    }

    #pragma unroll
    for (int orow = 0; orow < 8; orow++) {
        float4 o;
        o.x = acc[orow][0]; o.y = acc[orow][1];
        o.z = acc[orow][2]; o.w = acc[orow][3];
        *(float4*)&op[(size_t)(ty0 + tyl + orow) * W_ + gx0] = o;
    }
}

__global__ __launch_bounds__(256) void depthwise_kernel(
    const float* __restrict__ img,
    const float* __restrict__ g,       // (16, 144) post-gelu feats
    const float* __restrict__ lin_w,
    const float* __restrict__ lin_b,
    float* __restrict__ out)
{
    __shared__ float kv_lds[32];

    int bc   = blockIdx.y;          // 0..47  (b*3 + c)
    int b    = bc / C_;
    int tile = blockIdx.x;          // 0..31  (8 x-tiles, 4 y-tiles)
    int tyi  = tile >> 3;
    int txi  = tile & 7;
    int ty0  = tyi * TSY;
    int tx0  = txi * TSX;

    int tid = threadIdx.x;
    int tx  = (tid & 15) * 4;       // 0..60
    int tyl = (tid >> 4) * 8;       // 0..120

    const float* ip = img + (size_t)bc * H_ * W_;
    float* op       = out + (size_t)bc * H_ * W_;
    const float* gb = g + b * 144;

    if (txi >= 1 && txi <= 6)
        dw_tile_fused<true >(ip, op, gb, lin_w, lin_b, kv_lds,
                             ty0, tx0, tx, tyl, tid);
    else
        dw_tile_fused<false>(ip, op, gb, lin_w, lin_b, kv_lds,
                             ty0, tx0, tx, tyl, tid);
}

extern "C" void kernel_launch(void* const* d_in, const int* in_sizes, int n_in,
                              void* d_out, int out_size, void* d_ws, size_t ws_size,
                              hipStream_t stream) {
    const float* feature = (const float*)d_in[0];
    const float* img     = (const float*)d_in[1];
    const float* conv_w  = (const float*)d_in[2];
    const float* conv_b  = (const float*)d_in[3];
    const float* lin_w   = (const float*)d_in[4];
    const float* lin_b   = (const float*)d_in[5];
    float* out = (float*)d_out;

    float* g_ws = (float*)d_ws;             // 16*144 floats (post-gelu)

    patch_conv_kernel<<<B_ * 16, 256, 0, stream>>>(feature, conv_w, conv_b, g_ws);

    dim3 grid(32, B_ * C_);
    depthwise_kernel<<<grid, 256, 0, stream>>>(img, g_ws, lin_w, lin_b, out);
}

// Round 3
// 130.231 us; speedup vs baseline: 1.0369x; 1.0113x over previous
//
#include <hip/hip_runtime.h>
#include <math.h>

// Problem shapes
// feature: (16, 32, 64, 64) f32
// img:     (16, 3, 512, 512) f32
// conv_w:  (16, 32, 16, 16) f32   (OIHW)
// conv_b:  (16,)
// lin_w:   (25, 144)
// lin_b:   (25,)
// out:     (16, 3, 512, 512) f32

#define B_  16
#define C_  3
#define H_  512
#define W_  512

// ---------------------------------------------------------------------------
// Stage 1: 16x16 conv (pad=1) on the 16x16 feature patch + bias + exact gelu.
// One block per (b, oc); thread <-> spatial tap for all 32 input channels.
// Guard pad = 20 floats so the patch base is 16B-aligned -> float4 staging.
// ---------------------------------------------------------------------------
__global__ __launch_bounds__(256) void patch_conv_kernel(
    const float* __restrict__ feature,
    const float* __restrict__ conv_w,
    const float* __restrict__ conv_b,
    float* __restrict__ g_out)
{
    __shared__ __align__(16) float patch_raw[20 + 8192 + 20]; // guards +-17
    __shared__ float red[9][4];
    float* patch = patch_raw + 20;

    int blk = blockIdx.x;
    int b   = blk >> 4;
    int oc  = blk & 15;
    int tid = threadIdx.x;

    const float* fb = feature + (size_t)b * 32 * 4096;
    const float* wb = conv_w + (size_t)oc * 8192;

    if (tid < 20) { patch_raw[tid] = 0.f; patch_raw[20 + 8192 + tid] = 0.f; }

    // float4 staging: 2048 float4s, 16B-aligned src and dst
    for (int i = tid; i < 2048; i += 256) {
        int ic  = i >> 6;
        int r4  = i & 63;
        int row = r4 >> 2;
        int c4  = r4 & 3;
        float4 v = *(const float4*)(fb + (size_t)ic * 4096 + row * 64 + c4 * 4);
        *(float4*)(patch + ic * 256 + row * 16 + c4 * 4) = v;
    }

    float wreg[32];
    #pragma unroll
    for (int ic = 0; ic < 32; ic++) wreg[ic] = wb[ic * 256 + tid];

    __syncthreads();

    int kh = tid >> 4;
    int kw = tid & 15;

    float acc[9];
    #pragma unroll
    for (int k = 0; k < 9; k++) acc[k] = 0.f;

    #pragma unroll 4
    for (int ic = 0; ic < 32; ic++) {
        int base = ic * 256 + tid;
        float wv = wreg[ic];
        #pragma unroll
        for (int di = 0; di < 3; di++) {
            #pragma unroll
            for (int dj = 0; dj < 3; dj++) {
                acc[di * 3 + dj] += patch[base + (di - 1) * 16 + (dj - 1)] * wv;
            }
        }
    }

    #pragma unroll
    for (int di = 0; di < 3; di++) {
        #pragma unroll
        for (int dj = 0; dj < 3; dj++) {
            bool ok = ((unsigned)(kh + di - 1) < 16u) &&
                      ((unsigned)(kw + dj - 1) < 16u);
            if (!ok) acc[di * 3 + dj] = 0.f;
        }
    }

    #pragma unroll
    for (int k = 0; k < 9; k++) {
        float v = acc[k];
        #pragma unroll
        for (int off = 32; off > 0; off >>= 1)
            v += __shfl_xor(v, off, 64);
        acc[k] = v;
    }
    int wid  = tid >> 6;
    int lane = tid & 63;
    if (lane == 0) {
        #pragma unroll
        for (int k = 0; k < 9; k++) red[k][wid] = acc[k];
    }
    __syncthreads();
    if (tid < 9) {
        float s = red[tid][0] + red[tid][1] + red[tid][2] + red[tid][3];
        s += conv_b[oc];
        float g = 0.5f * s * (1.0f + erff(s * 0.70710678118654752f));
        g_out[(b * 16 + oc) * 9 + tid] = g;
    }
}

// ---------------------------------------------------------------------------
// Stage 2+3 fused: depthwise 5x5 conv, reflect pad=2, with the 25x144 GEMV
// recomputed redundantly per block (overlapped with the img row prefetch).
//
// Block tile 64 wide x 128 tall; 256 threads, each 4 wide x 8 tall.
// Each thread streams its 12 input rows through a 4-deep register window.
//
// MODE 0: interior x-tiles (txi 1..6) — unaligned vector loads, no reflect.
// MODE 1: edge x-tiles (txi 0,7) — clamped vector loads + static register
//         permute for the 1-in-16 lanes that touch the x-reflected border.
//         eL (gx0=0):   window = [l2,l1,l0,l1,l2,l3,l4,l5]  (xb=0)
//         eR (gx0=508): window = [l2,l3,l4,l5,l6,l7,l6,l5]  (xb=504)
// ---------------------------------------------------------------------------
#define TSX  64          // tile width
#define TSY  128         // tile height

__device__ __forceinline__ int reflect_idx(int v, int n) {
    v = (v < 0) ? -v : v;
    v = (v >= n) ? (2 * n - 2 - v) : v;
    return v;
}

template <int MODE>
struct RowIO {
    int gx0, xb;
    bool eL, eR;
    __device__ __forceinline__ void init(int gx0_) {
        gx0 = gx0_;
        if (MODE == 1) {
            xb = gx0 - 2;
            eL = (xb < 0);            // gx0 == 0
            eR = (xb > W_ - 8);       // gx0 == 508
            if (eL) xb = 0;
            if (eR) xb = W_ - 8;      // 504
        }
    }
    __device__ __forceinline__ void load(const float* __restrict__ rowp,
                                         float* __restrict__ wd) const {
        if (MODE == 0) {
            const float* rp = rowp + gx0;
            float2 a = *(const float2*)(rp - 2);
            float4 m = *(const float4*)(rp);
            float2 c = *(const float2*)(rp + 4);
            wd[0] = a.x; wd[1] = a.y;
            wd[2] = m.x; wd[3] = m.y; wd[4] = m.z; wd[5] = m.w;
            wd[6] = c.x; wd[7] = c.y;
        } else {
            const float* rp = rowp + xb;
            float2 a0 = *(const float2*)(rp + 0);
            float2 a1 = *(const float2*)(rp + 2);
            float2 a2 = *(const float2*)(rp + 4);
            float2 a3 = *(const float2*)(rp + 6);
            float l0 = a0.x, l1 = a0.y, l2 = a1.x, l3 = a1.y;
            float l4 = a2.x, l5 = a2.y, l6 = a3.x, l7 = a3.y;
            // interior lanes: identity. eL: [l2,l1,l0,l1,l2,l3,l4,l5].
            // eR: [l2,l3,l4,l5,l6,l7,l6,l5].
            wd[0] = (eL || eR) ? l2 : l0;
            wd[1] = eR ? l3 : l1;
            wd[2] = eL ? l0 : (eR ? l4 : l2);
            wd[3] = eL ? l1 : (eR ? l5 : l3);
            wd[4] = eL ? l2 : (eR ? l6 : l4);
            wd[5] = eL ? l3 : (eR ? l7 : l5);
            wd[6] = eL ? l4 : l6;
            wd[7] = (eL || eR) ? l5 : l7;   // eR: reflect(513)=509 -> l5
        }
    }
};

template <int MODE>
__device__ __forceinline__ void dw_tile_fused(
    const float* __restrict__ ip, float* __restrict__ op,
    const float* __restrict__ gb,      // g + b*144
    const float* __restrict__ lin_w,
    const float* __restrict__ lin_b,
    float* __restrict__ kv_lds,        // 32-float LDS scratch
    int ty0, int tx0, int tx, int tyl, int tid)
{
    int gx0 = tx0 + tx;            // x of this thread's first output column
    RowIO<MODE> io;
    io.init(gx0);

    float win[4][8];

    // prefetch rows 0..3 (VMEM in flight; GEMV below overlaps this latency)
    #pragma unroll
    for (int r = 0; r < 4; r++) {
        int gy = reflect_idx(ty0 + tyl + r - 2, H_);
        io.load(ip + (size_t)gy * W_, win[r]);
    }

    // ---- redundant per-block GEMV: kv[k] = lin_b[k] + sum_j gb[j]*lin_w[k,j]
    if (tid < 200) {
        int k = tid >> 3;          // 0..24
        int s = tid & 7;
        const float* wr = lin_w + k * 144;
        float p = 0.f;
        #pragma unroll
        for (int i = 0; i < 18; i++)
            p += gb[s + 8 * i] * wr[s + 8 * i];
        p += __shfl_xor(p, 1, 64);
        p += __shfl_xor(p, 2, 64);
        p += __shfl_xor(p, 4, 64);
        if (s == 0) kv_lds[k] = p + lin_b[k];
    }
    __syncthreads();

    // block-uniform kernel weights, forced to SGPRs
    float w[25];
    #pragma unroll
    for (int i = 0; i < 25; i++)
        w[i] = __int_as_float(
            __builtin_amdgcn_readfirstlane(__float_as_int(kv_lds[i])));

    float acc[8][4];
    #pragma unroll
    for (int i = 0; i < 8; i++)
        #pragma unroll
        for (int j = 0; j < 4; j++) acc[i][j] = 0.f;

    // stream 12 rows; consume row r, prefetch row r+4 into the freed slot
    #pragma unroll
    for (int r = 0; r < 12; r++) {
        const float* x = win[r & 3];
        #pragma unroll
        for (int orow = 0; orow < 8; orow++) {
            int dy = r - orow;
            if (dy >= 0 && dy < 5) {            // compile-time after unroll
                #pragma unroll
                for (int dx = 0; dx < 5; dx++) {
                    float wv = w[dy * 5 + dx];
                    #pragma unroll
                    for (int oc = 0; oc < 4; oc++)
                        acc[orow][oc] += wv * x[oc + dx];
                }
            }
        }
        if (r + 4 < 12) {
            int rn = r + 4;
            int gy = reflect_idx(ty0 + tyl + rn - 2, H_);
            io.load(ip + (size_t)gy * W_, win[r & 3]);
        }
    }

    #pragma unroll
    for (int orow = 0; orow < 8; orow++) {
        float4 o;
        o.x = acc[orow][0]; o.y = acc[orow][1];
        o.z = acc[orow][2]; o.w = acc[orow][3];
        *(float4*)&op[(size_t)(ty0 + tyl + orow) * W_ + gx0] = o;
    }
}

__global__ __launch_bounds__(256) void depthwise_kernel(
    const float* __restrict__ img,
    const float* __restrict__ g,       // (16, 144) post-gelu feats
    const float* __restrict__ lin_w,
    const float* __restrict__ lin_b,
    float* __restrict__ out)
{
    __shared__ float kv_lds[32];

    int bc   = blockIdx.y;          // 0..47  (b*3 + c)
    int b    = bc / C_;
    int tile = blockIdx.x;          // 0..31  (8 x-tiles, 4 y-tiles)
    int tyi  = tile >> 3;
    int txi  = tile & 7;
    int ty0  = tyi * TSY;
    int tx0  = txi * TSX;

    int tid = threadIdx.x;
    int tx  = (tid & 15) * 4;       // 0..60
    int tyl = (tid >> 4) * 8;       // 0..120

    const float* ip = img + (size_t)bc * H_ * W_;
    float* op       = out + (size_t)bc * H_ * W_;
    const float* gb = g + b * 144;

    if (txi >= 1 && txi <= 6)
        dw_tile_fused<0>(ip, op, gb, lin_w, lin_b, kv_lds,
                         ty0, tx0, tx, tyl, tid);
    else
        dw_tile_fused<1>(ip, op, gb, lin_w, lin_b, kv_lds,
                         ty0, tx0, tx, tyl, tid);
}

extern "C" void kernel_launch(void* const* d_in, const int* in_sizes, int n_in,
                              void* d_out, int out_size, void* d_ws, size_t ws_size,
                              hipStream_t stream) {
    const float* feature = (const float*)d_in[0];
    const float* img     = (const float*)d_in[1];
    const float* conv_w  = (const float*)d_in[2];
    const float* conv_b  = (const float*)d_in[3];
    const float* lin_w   = (const float*)d_in[4];
    const float* lin_b   = (const float*)d_in[5];
    float* out = (float*)d_out;

    float* g_ws = (float*)d_ws;             // 16*144 floats (post-gelu)

    patch_conv_kernel<<<B_ * 16, 256, 0, stream>>>(feature, conv_w, conv_b, g_ws);

    dim3 grid(32, B_ * C_);
    depthwise_kernel<<<grid, 256, 0, stream>>>(img, g_ws, lin_w, lin_b, out);
}